// Round 5
// baseline (103.145 us; speedup 1.0000x reference)
//
#include <hip/hip_runtime.h>
#include <stdint.h>

#define B_ 4
#define C_ 256
#define N_ 4096
#define LOG2E 1.44269504088896341f

typedef __attribute__((ext_vector_type(8))) short short8;
typedef __attribute__((ext_vector_type(4))) float f32x4;

__device__ __forceinline__ unsigned short f2bf(float f) {
    unsigned int u = __float_as_uint(f);
    u += 0x7FFFu + ((u >> 16) & 1u);
    return (unsigned short)(u >> 16);
}

// pack two f32 -> bf16 pair (round-half-up; inputs are finite softmax probs)
__device__ __forceinline__ unsigned int pack_bf(float a, float b) {
    return ((__float_as_uint(a) + 0x8000u) >> 16) |
           ((__float_as_uint(b) + 0x8000u) & 0xFFFF0000u);
}

// producer barrier: drain own LDS writes, then raw barrier (no vmcnt drain --
// keeps global prefetch loads in flight across the barrier, T4)
#define BAR_PROD() do { \
    asm volatile("s_waitcnt lgkmcnt(0)" ::: "memory"); \
    __builtin_amdgcn_s_barrier(); \
    asm volatile("" ::: "memory"); } while (0)
// consumer barrier: raw barrier only; compiler fence so LDS reads can't hoist
#define BAR_CONS() do { \
    __builtin_amdgcn_s_barrier(); \
    asm volatile("" ::: "memory"); } while (0)

// ---------------------------------------------------------------------------
// prep: pack W -> wb[320][256] bf16 (rows 0-31 Wq*(log2e/16), 32-63 Wk, 64-319 Wv),
//       biases -> bb[320] f32.  grid 320 x 64.
// ---------------------------------------------------------------------------
__global__ __launch_bounds__(64) void prep_kernel(
    const float* __restrict__ Wq, const float* __restrict__ bq,
    const float* __restrict__ Wk, const float* __restrict__ bk,
    const float* __restrict__ Wv, const float* __restrict__ bv,
    unsigned short* __restrict__ wb, float* __restrict__ bb)
{
    const int m = blockIdx.x;
    const int t = threadIdx.x;
    const float* src;
    float scale = 1.0f, bias;
    if (m < 32)      { src = Wq + m * C_;        scale = 0.0625f * LOG2E; bias = bq[m] * 0.0625f * LOG2E; }
    else if (m < 64) { src = Wk + (m - 32) * C_;                          bias = bk[m - 32]; }
    else             { src = Wv + (m - 64) * C_;                          bias = bv[m - 64]; }
    float4 v = *(const float4*)(src + t * 4);
    unsigned int lo = (unsigned int)f2bf(v.x * scale) | ((unsigned int)f2bf(v.y * scale) << 16);
    unsigned int hi = (unsigned int)f2bf(v.z * scale) | ((unsigned int)f2bf(v.w * scale) << 16);
    *(uint2*)(wb + m * C_ + t * 4) = make_uint2(lo, hi);
    if (t == 0) bb[m] = bias;
}

// ---------------------------------------------------------------------------
// proj (MFMA GEMM): D[m][n] = sum_k wb[m][k] * x[b][k][n]  (+bias)
// grid 256 = (b, n-tile of 64), 256 threads = 4 waves, wave w: m rows 80w..80w+79.
// ---------------------------------------------------------------------------
__global__ __launch_bounds__(256) void proj_kernel(
    const float* __restrict__ x,
    const unsigned short* __restrict__ wb, const float* __restrict__ bb,
    unsigned short* __restrict__ qT, unsigned short* __restrict__ kT,
    unsigned short* __restrict__ vb)
{
    __shared__ unsigned short xs[256][68];

    const int bid = ((blockIdx.x & 7) << 5) + (blockIdx.x >> 3);
    const int b = bid >> 6, n0 = (bid & 63) << 6;
    const int tid = threadIdx.x, wid = tid >> 6, lane = tid & 63;
    const int l15 = lane & 15, l4 = lane >> 4;

#pragma unroll
    for (int it = 0; it < 16; ++it) {
        int idx = it * 256 + tid;
        int k = idx >> 4, n4 = (idx & 15) << 2;
        float4 v = *(const float4*)(x + ((size_t)(b * C_ + k)) * N_ + n0 + n4);
        unsigned int lo = (unsigned int)f2bf(v.x) | ((unsigned int)f2bf(v.y) << 16);
        unsigned int hi = (unsigned int)f2bf(v.z) | ((unsigned int)f2bf(v.w) << 16);
        *(uint2*)&xs[k][n4] = make_uint2(lo, hi);
    }
    __syncthreads();

    const int m0 = wid * 80;
    f32x4 acc[5][4];
#pragma unroll
    for (int mf = 0; mf < 5; ++mf)
#pragma unroll
        for (int nt = 0; nt < 4; ++nt)
            acc[mf][nt] = (f32x4){0.f, 0.f, 0.f, 0.f};

#pragma unroll
    for (int s = 0; s < 8; ++s) {
        short8 wf[5];
#pragma unroll
        for (int mf = 0; mf < 5; ++mf)
            wf[mf] = *(const short8*)(wb + (size_t)(m0 + 16 * mf + l15) * C_ + 32 * s + 8 * l4);
        short8 xf[4];
#pragma unroll
        for (int nt = 0; nt < 4; ++nt) {
#pragma unroll
            for (int e = 0; e < 8; ++e)
                xf[nt][e] = (short)xs[32 * s + 8 * l4 + e][16 * nt + l15];
        }
#pragma unroll
        for (int mf = 0; mf < 5; ++mf)
#pragma unroll
            for (int nt = 0; nt < 4; ++nt)
                acc[mf][nt] = __builtin_amdgcn_mfma_f32_16x16x32_bf16(wf[mf], xf[nt], acc[mf][nt], 0, 0, 0);
    }

#pragma unroll
    for (int mf = 0; mf < 5; ++mf) {
        const int mbase = m0 + 16 * mf + 4 * l4;
        const float4 b4 = *(const float4*)(bb + mbase);
        const int region = (m0 + 16 * mf) >> 5;
#pragma unroll
        for (int nt = 0; nt < 4; ++nt) {
            const int n = n0 + 16 * nt + l15;
            float o0 = acc[mf][nt][0] + b4.x;
            float o1 = acc[mf][nt][1] + b4.y;
            float o2 = acc[mf][nt][2] + b4.z;
            float o3 = acc[mf][nt][3] + b4.w;
            if (region == 0) {
                *(uint2*)(qT + ((size_t)(b * N_ + n)) * 32 + mbase) =
                    make_uint2(pack_bf(o0, o1), pack_bf(o2, o3));
            } else if (region == 1) {
                *(uint2*)(kT + ((size_t)(b * N_ + n)) * 32 + (mbase - 32)) =
                    make_uint2(pack_bf(o0, o1), pack_bf(o2, o3));
            } else {
                const int c = mbase - 64;
                vb[((size_t)(b * C_ + c + 0)) * N_ + n] = f2bf(o0);
                vb[((size_t)(b * C_ + c + 1)) * N_ + n] = f2bf(o1);
                vb[((size_t)(b * C_ + c + 2)) * N_ + n] = f2bf(o2);
                vb[((size_t)(b * C_ + c + 3)) * N_ + n] = f2bf(o3);
            }
        }
    }
}

// ---------------------------------------------------------------------------
// attn: producer-consumer flash attention, counted-wait barriers.
// grid 256 blocks (b, 64 q-rows), 512 threads = 8 waves.
// waves 0-3 (QK): swapped QK^T + online softmax; publish P(bf16)+scale (dbuf LDS).
// waves 4-7 (PV): consume P(t-1), V-frags direct from L2 (reg ping-pong).
// One raw barrier per tile per side; global prefetches stay in flight.
// ---------------------------------------------------------------------------
__global__ __launch_bounds__(512, 2) void attn_kernel(
    const unsigned short* __restrict__ qT, const unsigned short* __restrict__ kT,
    const unsigned short* __restrict__ vbuf, const float* __restrict__ x,
    const float* __restrict__ gamma, float* __restrict__ out)
{
    __shared__ unsigned short Pl[2][64][72];   // [buf][q][j] bf16
    __shared__ float sc_l[2][64];              // [buf][q] rescale factors
    __shared__ float sum_l[64];                // final denominators

    const int bid = ((blockIdx.x & 7) << 5) + (blockIdx.x >> 3);  // batch -> 2 XCDs
    const int b = bid >> 6, i0 = (bid & 63) << 6;
    const int tid = threadIdx.x, wid = tid >> 6, lane = tid & 63;
    const int l15 = lane & 15, l4 = lane >> 4;
    const f32x4 zero = {0.f, 0.f, 0.f, 0.f};

    if (wid < 4) {
        // ================= QK / softmax producer =================
        const short8 qfrag = *(const short8*)(
            qT + ((size_t)(b * N_ + i0 + 16 * wid + l15)) * 32 + 8 * l4);
        const unsigned short* kbase = kT + ((size_t)b * N_ + l15) * 32 + 8 * l4;

        short8 ka[4], kb_[4];
        _Pragma("unroll")
        for (int f = 0; f < 4; ++f)
            ka[f] = *(const short8*)(kbase + (size_t)(16 * f) * 32);

        float m = -1e30f, l = 0.f;

#define QK_BODY(T, KC, KN)                                                        \
  {                                                                               \
    if ((T) < 63) {                                                               \
      _Pragma("unroll")                                                           \
      for (int f = 0; f < 4; ++f)                                                 \
        KN[f] = *(const short8*)(kbase + (size_t)(((T) + 1) * 64 + 16 * f) * 32); \
    }                                                                             \
    f32x4 sv[4];                                                                  \
    _Pragma("unroll")                                                             \
    for (int f = 0; f < 4; ++f)                                                   \
      sv[f] = __builtin_amdgcn_mfma_f32_16x16x32_bf16(KC[f], qfrag, zero, 0, 0, 0);\
    float mx = sv[0][0];                                                          \
    _Pragma("unroll")                                                             \
    for (int f = 0; f < 4; ++f) {                                                 \
      _Pragma("unroll")                                                           \
      for (int r = 0; r < 4; ++r) mx = fmaxf(mx, sv[f][r]);                       \
    }                                                                             \
    mx = fmaxf(mx, __shfl_xor(mx, 16, 64));                                       \
    mx = fmaxf(mx, __shfl_xor(mx, 32, 64));                                       \
    const float mn = fmaxf(m, mx);                                                \
    const float scf = exp2f(m - mn);                                              \
    m = mn;                                                                       \
    float ps = 0.f;                                                               \
    _Pragma("unroll")                                                             \
    for (int f = 0; f < 4; ++f) {                                                 \
      _Pragma("unroll")                                                           \
      for (int r = 0; r < 4; ++r) { sv[f][r] = exp2f(sv[f][r] - mn); ps += sv[f][r]; } \
    }                                                                             \
    ps += __shfl_xor(ps, 16, 64);                                                 \
    ps += __shfl_xor(ps, 32, 64);                                                 \
    l = l * scf + ps;                                                             \
    unsigned short* prow = &Pl[(T) & 1][16 * wid + l15][4 * l4];                  \
    _Pragma("unroll")                                                             \
    for (int f = 0; f < 4; ++f)                                                   \
      *(uint2*)(prow + 16 * f) = make_uint2(pack_bf(sv[f][0], sv[f][1]),          \
                                            pack_bf(sv[f][2], sv[f][3]));         \
    if (l4 == 0) sc_l[(T) & 1][16 * wid + l15] = scf;                             \
  }

        for (int u = 0; u < 32; ++u) {
            QK_BODY(2 * u, ka, kb_)
            BAR_PROD();
            QK_BODY(2 * u + 1, kb_, ka)
            BAR_PROD();
        }
        if (l4 == 0) sum_l[16 * wid + l15] = l;
        BAR_PROD();
        // QK waves exit
    } else {
        // ================= PV consumer =================
        const int c0 = (wid - 4) << 6;
        const unsigned short* vrow[4];
        _Pragma("unroll")
        for (int nb = 0; nb < 4; ++nb)
            vrow[nb] = vbuf + ((size_t)(b * C_ + c0 + 16 * nb + l15)) * N_ + 8 * l4;

        f32x4 acc[4][4];
        _Pragma("unroll")
        for (int qf = 0; qf < 4; ++qf) {
            _Pragma("unroll")
            for (int nb = 0; nb < 4; ++nb)
                acc[qf][nb] = (f32x4){0.f, 0.f, 0.f, 0.f};
        }

        short8 va_[4][2], vb2_[4][2];

#define PV_LOAD(DST, T)                                                           \
    {                                                                             \
      _Pragma("unroll")                                                           \
      for (int nb = 0; nb < 4; ++nb) {                                            \
        _Pragma("unroll")                                                         \
        for (int kb = 0; kb < 2; ++kb)                                            \
          DST[nb][kb] = *(const short8*)(vrow[nb] + (T) * 64 + kb * 32);          \
      }                                                                           \
    }

#define PV_BODY(T, VC, VN)                                                        \
  {                                                                               \
    if ((T) >= 1 && (T) < 64) PV_LOAD(VN, (T))                                    \
    const int bf = ((T) + 1) & 1; /* == (T-1)&1 */                                \
    short8 pa[4][2];                                                              \
    _Pragma("unroll")                                                             \
    for (int qf = 0; qf < 4; ++qf) {                                              \
      _Pragma("unroll")                                                           \
      for (int kb = 0; kb < 2; ++kb)                                              \
        pa[qf][kb] = *(const short8*)&Pl[bf][16 * qf + l15][kb * 32 + 8 * l4];    \
    }                                                                             \
    f32x4 scv_[4];                                                                \
    bool need = false;                                                            \
    _Pragma("unroll")                                                             \
    for (int qf = 0; qf < 4; ++qf) {                                              \
      scv_[qf] = *(const f32x4*)&sc_l[bf][16 * qf + 4 * l4];                      \
      _Pragma("unroll")                                                           \
      for (int r = 0; r < 4; ++r) need = need || (scv_[qf][r] != 1.0f);           \
    }                                                                             \
    if (__any(need)) {                                                            \
      _Pragma("unroll")                                                           \
      for (int qf = 0; qf < 4; ++qf) {                                            \
        _Pragma("unroll")                                                         \
        for (int nb = 0; nb < 4; ++nb) {                                          \
          _Pragma("unroll")                                                       \
          for (int r = 0; r < 4; ++r) acc[qf][nb][r] *= scv_[qf][r];              \
        }                                                                         \
      }                                                                           \
    }                                                                             \
    __builtin_amdgcn_s_setprio(1);                                                \
    _Pragma("unroll")                                                             \
    for (int qf = 0; qf < 4; ++qf) {                                              \
      _Pragma("unroll")                                                           \
      for (int kb = 0; kb < 2; ++kb) {                                            \
        _Pragma("unroll")                                                         \
        for (int nb = 0; nb < 4; ++nb)                                            \
          acc[qf][nb] = __builtin_amdgcn_mfma_f32_16x16x32_bf16(pa[qf][kb], VC[nb][kb], acc[qf][nb], 0, 0, 0); \
      }                                                                           \
    }                                                                             \
    __builtin_amdgcn_s_setprio(0);                                                \
  }

        PV_LOAD(vb2_, 0)          // prologue: tile 0
        BAR_CONS();               // matches QK's barrier after body 0
        for (int u = 0; u < 32; ++u) {
            PV_BODY(2 * u + 1, vb2_, va_)
            BAR_CONS();
            PV_BODY(2 * u + 2, va_, vb2_)
            BAR_CONS();
        }

        // epilogue: out = gamma/l * acc + x
        const float gm = gamma[0];
        _Pragma("unroll")
        for (int qf = 0; qf < 4; ++qf) {
            const f32x4 lv = *(const f32x4*)&sum_l[16 * qf + 4 * l4];
            float inv[4];
            _Pragma("unroll")
            for (int r = 0; r < 4; ++r) inv[r] = gm / lv[r];
            _Pragma("unroll")
            for (int nb = 0; nb < 4; ++nb) {
                const size_t oidx = ((size_t)(b * C_ + c0 + 16 * nb + l15)) * N_
                                    + i0 + 16 * qf + 4 * l4;
                const float4 xr = *(const float4*)(x + oidx);
                float4 res;
                res.x = acc[qf][nb][0] * inv[0] + xr.x;
                res.y = acc[qf][nb][1] * inv[1] + xr.y;
                res.z = acc[qf][nb][2] * inv[2] + xr.z;
                res.w = acc[qf][nb][3] * inv[3] + xr.w;
                *(float4*)(out + oidx) = res;
            }
        }
    }
}

extern "C" void kernel_launch(void* const* d_in, const int* in_sizes, int n_in,
                              void* d_out, int out_size, void* d_ws, size_t ws_size,
                              hipStream_t stream) {
    (void)in_sizes; (void)n_in; (void)out_size; (void)ws_size;
    const float* x  = (const float*)d_in[0];
    const float* Wq = (const float*)d_in[1];
    const float* bq = (const float*)d_in[2];
    const float* Wk = (const float*)d_in[3];
    const float* bk = (const float*)d_in[4];
    const float* Wv = (const float*)d_in[5];
    const float* bv = (const float*)d_in[6];
    const float* gm = (const float*)d_in[7];
    float* out = (float*)d_out;

    char* ws = (char*)d_ws;
    unsigned short* wb = (unsigned short*)ws;                                // 160 KB
    float*          bb = (float*)(ws + 320 * 256 * 2);                       // 1.25 KB
    unsigned short* qT = (unsigned short*)(ws + 320 * 256 * 2 + 320 * 4);    // 1 MB
    unsigned short* kT = qT + (size_t)B_ * N_ * 32;                          // 1 MB
    unsigned short* vb = kT + (size_t)B_ * N_ * 32;                          // 8 MB

    hipLaunchKernelGGL(prep_kernel, dim3(320), dim3(64), 0, stream,
                       Wq, bq, Wk, bk, Wv, bv, wb, bb);
    hipLaunchKernelGGL(proj_kernel, dim3(256), dim3(256), 0, stream,
                       x, wb, bb, qT, kT, vb);
    hipLaunchKernelGGL(attn_kernel, dim3(256), dim3(512), 0, stream,
                       qT, kT, vb, x, gm, out);
}